// Round 4
// baseline (216.371 us; speedup 1.0000x reference)
//
#include <hip/hip_runtime.h>
#include <stdint.h>

typedef unsigned short u16;
typedef unsigned int u32;
typedef __bf16 bf16x8 __attribute__((ext_vector_type(8)));
typedef float f32x4 __attribute__((ext_vector_type(4)));

// ---------- helpers ----------
__device__ __forceinline__ float bf2f(u16 u) {
  return __builtin_bit_cast(float, (u32)u << 16);
}
__device__ __forceinline__ u16 f2b(float f) {
  u32 u = __builtin_bit_cast(u32, f);
  u32 r = (u + 0x7fffu + ((u >> 16) & 1u)) >> 16;  // RNE
  return (u16)r;
}
__device__ __forceinline__ void gload16(const u16* g, u16* l) {
  __builtin_amdgcn_global_load_lds(
      (const __attribute__((address_space(1))) u32*)(const void*)g,
      (__attribute__((address_space(3))) u32*)(void*)l, 16, 0, 0);
}
__device__ __forceinline__ void unpack16(uint4 a, uint4 b, float* o) {
  u32 w[8] = {a.x, a.y, a.z, a.w, b.x, b.y, b.z, b.w};
#pragma unroll
  for (int i = 0; i < 8; ++i) {
    o[2 * i]     = __builtin_bit_cast(float, w[i] << 16);
    o[2 * i + 1] = __builtin_bit_cast(float, w[i] & 0xffff0000u);
  }
}

// ---------- fp32 -> bf16 convert ----------
__global__ __launch_bounds__(256) void cvt_bf16(const float* __restrict__ in,
                                                u16* __restrict__ out, int n4) {
  int i = blockIdx.x * 256 + threadIdx.x;
  if (i >= n4) return;
  float4 v = reinterpret_cast<const float4*>(in)[i];
  ushort4 o;
  o.x = f2b(v.x); o.y = f2b(v.y); o.z = f2b(v.z); o.w = f2b(v.w);
  reinterpret_cast<ushort4*>(out)[i] = o;
}

// ---------- bf16 GEMM  C[M,N] = A[M,K] * B[N,K]^T  (both row-major, K contig) ----------
// 128x128 tile, BK=32, 4 waves (2x2), acc 4x4 frags of 16x16x32 MFMA. m97-style.
// MODE 0: bf16 out, fused per-head LN on q/k column sections (wave col span = 64
//         = exactly one head slice; row stats via 16-lane shfl reduce).
// MODE 1: fp32 out + bias.
template <int MODE>
__global__ __launch_bounds__(256) void gemm_bt(
    const u16* __restrict__ A, const u16* __restrict__ B, void* __restrict__ C,
    const float* __restrict__ gq, const float* __restrict__ bq,
    const float* __restrict__ gk, const float* __restrict__ bk,
    const float* __restrict__ bias, int M, int N, int K, int ntn) {
  __shared__ u16 As[128 * 32];
  __shared__ u16 Bs[128 * 32];
  int bid = blockIdx.x;
  int tm = bid / ntn, tn = bid % ntn;
  int brow = tm << 7, bcol = tn << 7;
  int tid = threadIdx.x;
  int w = tid >> 6, lane = tid & 63;
  int wrow = (w >> 1) << 6, wcol = (w & 1) << 6;
  int lr = lane & 15, lk = (lane >> 4) << 3;

  const u16* Ag = A + (size_t)(brow + (lane >> 2)) * K + ((lane & 3) << 3);
  const u16* Bg = B + (size_t)(bcol + (lane >> 2)) * K + ((lane & 3) << 3);

  f32x4 acc[4][4];
#pragma unroll
  for (int m = 0; m < 4; ++m)
#pragma unroll
    for (int n = 0; n < 4; ++n) acc[m][n] = (f32x4){0.f, 0.f, 0.f, 0.f};

  for (int k0 = 0; k0 < K; k0 += 32) {
    if (k0) __syncthreads();  // previous tile fully consumed before overwrite
#pragma unroll
    for (int c = 0; c < 2; ++c) {
      int ch = w * 2 + c;  // 8 chunks of 16 rows, wave-uniform LDS base
      gload16(Ag + (size_t)ch * 16 * K + k0, &As[ch * 512]);
      gload16(Bg + (size_t)ch * 16 * K + k0, &Bs[ch * 512]);
    }
    asm volatile("s_waitcnt vmcnt(0)" ::: "memory");
    __syncthreads();

    bf16x8 af[4], bfr[4];
#pragma unroll
    for (int m = 0; m < 4; ++m)
      af[m] = *reinterpret_cast<const bf16x8*>(&As[(wrow + m * 16 + lr) * 32 + lk]);
#pragma unroll
    for (int n = 0; n < 4; ++n)
      bfr[n] = *reinterpret_cast<const bf16x8*>(&Bs[(wcol + n * 16 + lr) * 32 + lk]);
#pragma unroll
    for (int m = 0; m < 4; ++m)
#pragma unroll
      for (int n = 0; n < 4; ++n)
        acc[m][n] = __builtin_amdgcn_mfma_f32_16x16x32_bf16(af[m], bfr[n], acc[m][n], 0, 0, 0);
  }

  // C/D layout: col = lane&15, row = (lane>>4)*4 + reg
  const int orow = brow + wrow + ((lane >> 4) << 2);
  const int ocol = bcol + wcol + lr;
  if (MODE == 0) {
    const int wcol0 = bcol + wcol;  // 64-aligned -> exactly one head slice
    const int sect = wcol0 >> 6;    // 0..7 q, 8..15 k, 16..23 v
    const bool doln = sect < 16;
    const float* Gp = (sect < 8) ? (gq + wcol0) : (gk + (wcol0 - 512));
    const float* Pp = (sect < 8) ? (bq + wcol0) : (bk + (wcol0 - 512));
    float gv[4], pv[4];
    if (doln) {
#pragma unroll
      for (int n = 0; n < 4; ++n) { gv[n] = Gp[n * 16 + lr]; pv[n] = Pp[n * 16 + lr]; }
    }
    u16* Cp = (u16*)C;
#pragma unroll
    for (int m = 0; m < 4; ++m)
#pragma unroll
      for (int r = 0; r < 4; ++r) {
        size_t rowoff = (size_t)(orow + m * 16 + r) * N;
        if (doln) {
          float s = 0.f, s2 = 0.f;
#pragma unroll
          for (int n = 0; n < 4; ++n) {
            float x = acc[m][n][r];
            s += x; s2 += x * x;
          }
#pragma unroll
          for (int off = 8; off; off >>= 1) {
            s += __shfl_xor(s, off, 64);
            s2 += __shfl_xor(s2, off, 64);
          }
          float mean = s * 0.015625f;
          float inv = rsqrtf(s2 * 0.015625f - mean * mean + 1e-5f);
#pragma unroll
          for (int n = 0; n < 4; ++n)
            Cp[rowoff + ocol + n * 16] =
                f2b((acc[m][n][r] - mean) * inv * gv[n] + pv[n]);
        } else {
#pragma unroll
          for (int n = 0; n < 4; ++n)
            Cp[rowoff + ocol + n * 16] = f2b(acc[m][n][r]);
        }
      }
  } else {
    float bvv[4];
#pragma unroll
    for (int n = 0; n < 4; ++n) bvv[n] = bias[ocol + n * 16];
    float* Cp = (float*)C;
#pragma unroll
    for (int m = 0; m < 4; ++m)
#pragma unroll
      for (int r = 0; r < 4; ++r) {
        size_t rowoff = (size_t)(orow + m * 16 + r) * N;
#pragma unroll
        for (int n = 0; n < 4; ++n)
          Cp[rowoff + ocol + n * 16] = acc[m][n][r] + bvv[n];
      }
  }
}

// ---------- KV[b,h,d,e] += sum_n k[n,d]*v[n,e]  (atomic partials over n-chunks) ----------
__global__ __launch_bounds__(256) void kv_accum(const u16* __restrict__ qkv,
                                                float* __restrict__ KV) {
  int nch = blockIdx.x & 7;   // 8 chunks of 512 rows
  int bh = blockIdx.x >> 3;   // 0..31
  int b = bh >> 3, h = bh & 7;
  __shared__ float ks[64][64];
  __shared__ float vs[64][64];
  int tid = threadIdx.x;
  int ty = tid >> 4, tx = tid & 15;
  int rr = tid >> 2, cc = (tid & 3) * 16;
  float acc[4][4];
#pragma unroll
  for (int i = 0; i < 4; ++i)
#pragma unroll
    for (int j = 0; j < 4; ++j) acc[i][j] = 0.f;

  for (int t = 0; t < 8; ++t) {
    int n0 = nch * 512 + t * 64;
    __syncthreads();
    size_t base = ((size_t)(b * 4096 + n0 + rr)) * 1536 + h * 64 + cc;
    const uint4* kp = reinterpret_cast<const uint4*>(&qkv[base + 512]);
    const uint4* vp = reinterpret_cast<const uint4*>(&qkv[base + 1024]);
    uint4 k0 = kp[0], k1 = kp[1];
    uint4 v0 = vp[0], v1 = vp[1];
    unpack16(k0, k1, &ks[rr][cc]);
    unpack16(v0, v1, &vs[rr][cc]);
    __syncthreads();
    for (int n = 0; n < 64; ++n) {
      float4 k4 = *reinterpret_cast<const float4*>(&ks[n][ty * 4]);
      float4 v4 = *reinterpret_cast<const float4*>(&vs[n][tx * 4]);
      float ka[4] = {k4.x, k4.y, k4.z, k4.w};
      float va[4] = {v4.x, v4.y, v4.z, v4.w};
#pragma unroll
      for (int i = 0; i < 4; ++i)
#pragma unroll
        for (int j = 0; j < 4; ++j) acc[i][j] += ka[i] * va[j];
    }
  }
  float* dst = KV + (size_t)bh * 4096;
#pragma unroll
  for (int i = 0; i < 4; ++i)
#pragma unroll
    for (int j = 0; j < 4; ++j)
      atomicAdd(&dst[(ty * 4 + i) * 64 + tx * 4 + j], acc[i][j]);
}

// ---------- attn[n, h*64+e] = scale * sum_d qn[n,d] * KV[b,h,d,e] ----------
__global__ __launch_bounds__(256) void attn_kernel(const u16* __restrict__ qkv,
                                                   const float* __restrict__ KV,
                                                   u16* __restrict__ attn) {
  int rblk = blockIdx.x;  // 64 rows per block, 256 blocks
  int b = rblk >> 6;
  __shared__ float qs[64][65];
  __shared__ float kvs[64][64];
  int tid = threadIdx.x;
  int ty = tid >> 4, tx = tid & 15;
  int rr = tid >> 2, cc = (tid & 3) * 16;
  const float scale = 1.0f / 32768.0f;  // 1/(sqrt(64)*4096)
  for (int h = 0; h < 8; ++h) {
    __syncthreads();
    size_t qbase = ((size_t)(rblk * 64 + rr)) * 1536 + h * 64 + cc;
    const uint4* qp = reinterpret_cast<const uint4*>(&qkv[qbase]);
    uint4 q0 = qp[0], q1 = qp[1];
    unpack16(q0, q1, &qs[rr][cc]);
    const float4* kp =
        reinterpret_cast<const float4*>(&KV[((size_t)(b * 8 + h)) * 4096 + rr * 64 + cc]);
#pragma unroll
    for (int j = 0; j < 4; ++j) {
      float4 t = kp[j];
      kvs[rr][cc + 4 * j + 0] = t.x;
      kvs[rr][cc + 4 * j + 1] = t.y;
      kvs[rr][cc + 4 * j + 2] = t.z;
      kvs[rr][cc + 4 * j + 3] = t.w;
    }
    __syncthreads();
    float acc[4][4] = {};
    for (int d = 0; d < 64; ++d) {
      float a0 = qs[ty * 4 + 0][d], a1 = qs[ty * 4 + 1][d];
      float a2 = qs[ty * 4 + 2][d], a3 = qs[ty * 4 + 3][d];
      float4 bv = *reinterpret_cast<const float4*>(&kvs[d][tx * 4]);
      float ba[4] = {bv.x, bv.y, bv.z, bv.w};
#pragma unroll
      for (int j = 0; j < 4; ++j) {
        acc[0][j] += a0 * ba[j];
        acc[1][j] += a1 * ba[j];
        acc[2][j] += a2 * ba[j];
        acc[3][j] += a3 * ba[j];
      }
    }
#pragma unroll
    for (int i = 0; i < 4; ++i) {
      int row = rblk * 64 + ty * 4 + i;
      ushort4 o;
      o.x = f2b(acc[i][0] * scale);
      o.y = f2b(acc[i][1] * scale);
      o.z = f2b(acc[i][2] * scale);
      o.w = f2b(acc[i][3] * scale);
      *reinterpret_cast<ushort4*>(&attn[(size_t)row * 512 + h * 64 + tx * 4]) = o;
    }
  }
}

// ---------- launch ----------
extern "C" void kernel_launch(void* const* d_in, const int* in_sizes, int n_in,
                              void* d_out, int out_size, void* d_ws, size_t ws_size,
                              hipStream_t stream) {
  const float* x  = (const float*)d_in[0];
  const float* Wq = (const float*)d_in[1];
  const float* gq = (const float*)d_in[2];
  const float* bq = (const float*)d_in[3];
  const float* gk = (const float*)d_in[4];
  const float* bk = (const float*)d_in[5];
  const float* Wo = (const float*)d_in[6];
  const float* bo = (const float*)d_in[7];
  float* out = (float*)d_out;

  char* p = (char*)d_ws;
  auto carve = [&](size_t bytes) {
    char* r = p;
    p += (bytes + 255) & ~(size_t)255;
    return r;
  };
  u16* xb    = (u16*)carve((size_t)16384 * 1024 * 2);
  u16* wqb   = (u16*)carve((size_t)1536 * 1024 * 2);
  u16* wob   = (u16*)carve((size_t)1024 * 512 * 2);
  u16* qkv   = (u16*)carve((size_t)16384 * 1536 * 2);
  float* KVb = (float*)carve((size_t)32 * 64 * 64 * 4);
  u16* attn  = (u16*)carve((size_t)16384 * 512 * 2);

  hipMemsetAsync(KVb, 0, (size_t)32 * 64 * 64 * 4, stream);
  cvt_bf16<<<16384, 256, 0, stream>>>(x, xb, 4194304);
  cvt_bf16<<<1536, 256, 0, stream>>>(Wq, wqb, 393216);
  cvt_bf16<<<512, 256, 0, stream>>>(Wo, wob, 131072);
  // qkv = x @ Wqkv^T  [16384,1536], fused per-head LN on q,k
  gemm_bt<0><<<128 * 12, 256, 0, stream>>>(xb, wqb, qkv, gq, bq, gk, bk, nullptr,
                                           16384, 1536, 1024, 12);
  // KV = k^T v per (b,h)
  kv_accum<<<256, 256, 0, stream>>>(qkv, KVb);
  // attn = scale * q @ KV
  attn_kernel<<<256, 256, 0, stream>>>(qkv, KVb, attn);
  // out = attn @ Wout^T + b_out  [16384,1024] fp32
  gemm_bt<1><<<128 * 8, 256, 0, stream>>>(attn, wob, out, nullptr, nullptr, nullptr,
                                          nullptr, bo, 16384, 1024, 512, 8);
}

// Round 5
// 203.276 us; speedup vs baseline: 1.0644x; 1.0644x over previous
//
#include <hip/hip_runtime.h>
#include <stdint.h>

typedef unsigned short u16;
typedef unsigned int u32;
typedef __bf16 bf16x8 __attribute__((ext_vector_type(8)));
typedef float f32x4 __attribute__((ext_vector_type(4)));

// ---------- helpers ----------
__device__ __forceinline__ float bf2f(u16 u) {
  return __builtin_bit_cast(float, (u32)u << 16);
}
__device__ __forceinline__ u16 f2b(float f) {
  u32 u = __builtin_bit_cast(u32, f);
  u32 r = (u + 0x7fffu + ((u >> 16) & 1u)) >> 16;  // RNE
  return (u16)r;
}
__device__ __forceinline__ void gload16(const u16* g, u16* l) {
  __builtin_amdgcn_global_load_lds(
      (const __attribute__((address_space(1))) u32*)(const void*)g,
      (__attribute__((address_space(3))) u32*)(void*)l, 16, 0, 0);
}
__device__ __forceinline__ void unpack16(uint4 a, uint4 b, float* o) {
  u32 w[8] = {a.x, a.y, a.z, a.w, b.x, b.y, b.z, b.w};
#pragma unroll
  for (int i = 0; i < 8; ++i) {
    o[2 * i]     = __builtin_bit_cast(float, w[i] << 16);
    o[2 * i + 1] = __builtin_bit_cast(float, w[i] & 0xffff0000u);
  }
}

// ---------- fp32 -> bf16 convert ----------
__global__ __launch_bounds__(256) void cvt_bf16(const float* __restrict__ in,
                                                u16* __restrict__ out, int n4) {
  int i = blockIdx.x * 256 + threadIdx.x;
  if (i >= n4) return;
  float4 v = reinterpret_cast<const float4*>(in)[i];
  ushort4 o;
  o.x = f2b(v.x); o.y = f2b(v.y); o.z = f2b(v.z); o.w = f2b(v.w);
  reinterpret_cast<ushort4*>(out)[i] = o;
}

// ---------- bf16 GEMM  C[M,N] = A[M,K] * B[N,K]^T ----------
// 128x128 tile, BK=32, 4 waves (2x2), 16x16x32 MFMA.
// Triple-buffered LDS + counted vmcnt: chunk c computed only after vmcnt
// retires all loads older than the 2 newest chunks (4 loads/wave/chunk ->
// vmcnt(8)); buf[c%3] is re-staged with chunk c+3 only after the
// post-compute barrier. Tail: vmcnt(4) then vmcnt(0).
// LDS bank swizzle: 16B-slot s -> s ^ ((row>>1)&3), applied on the global
// SOURCE of global_load_lds (linear dest) and on the ds_read address.
// MODE 0: bf16 out + fused per-head LN (wave col span 64 = one head slice).
// MODE 1: fp32 out + bias.
template <int MODE>
__global__ __launch_bounds__(256) void gemm_bt(
    const u16* __restrict__ A, const u16* __restrict__ B, void* __restrict__ C,
    const float* __restrict__ gq, const float* __restrict__ bq,
    const float* __restrict__ gk, const float* __restrict__ bk,
    const float* __restrict__ bias, int M, int N, int K, int ntn) {
  __shared__ u16 As[3][128 * 32];
  __shared__ u16 Bs[3][128 * 32];

  // XCD-aware bijective swizzle (grid % 8 == 0 at both call sites)
  const int nwg = gridDim.x;
  const int bid0 = blockIdx.x;
  const int bid = (bid0 & 7) * (nwg >> 3) + (bid0 >> 3);
  const int tm = bid / ntn, tn = bid % ntn;
  const int brow = tm << 7, bcol = tn << 7;
  const int tid = threadIdx.x;
  const int w = tid >> 6, lane = tid & 63;
  const int wrow = (w >> 1) << 6, wcol = (w & 1) << 6;
  const int lr = lane & 15, lg = lane >> 4;

  // staging: lane l covers LDS (row = ch*16 + l/4, slot = l%4); source column
  // slot pre-swizzled so LDS(r,s) holds global slot s^((r>>1)&3).
  const int srow = lane >> 2;
  const int sslot = (lane & 3) ^ ((lane >> 3) & 3);
  const u16* Ag = A + (size_t)(brow + srow) * K + (sslot << 3);
  const u16* Bg = B + (size_t)(bcol + srow) * K + (sslot << 3);

  auto stage = [&](int c, int buf) {
    const int k0 = c << 5;
#pragma unroll
    for (int cc = 0; cc < 2; ++cc) {
      int ch = w * 2 + cc;  // 8 chunks of 16 rows, wave-uniform LDS base
      gload16(Ag + (size_t)ch * 16 * K + k0, &As[buf][ch * 512]);
      gload16(Bg + (size_t)ch * 16 * K + k0, &Bs[buf][ch * 512]);
    }
  };

  f32x4 acc[4][4];
#pragma unroll
  for (int m = 0; m < 4; ++m)
#pragma unroll
    for (int n = 0; n < 4; ++n) acc[m][n] = (f32x4){0.f, 0.f, 0.f, 0.f};

  const int NC = K >> 5;
  stage(0, 0);
  stage(1, 1);
  stage(2, 2);

  const int kslot = (lg ^ ((lr >> 1) & 3)) << 3;  // swizzled 16B slot (elems)

  int buf = 0;
  for (int c = 0; c < NC; ++c) {
    if (c + 2 < NC)
      asm volatile("s_waitcnt vmcnt(8)" ::: "memory");
    else if (c + 1 < NC)
      asm volatile("s_waitcnt vmcnt(4)" ::: "memory");
    else
      asm volatile("s_waitcnt vmcnt(0)" ::: "memory");
    __builtin_amdgcn_s_barrier();
    asm volatile("" ::: "memory");

    const u16* Asb = As[buf];
    const u16* Bsb = Bs[buf];
    bf16x8 af[4], bfr[4];
#pragma unroll
    for (int m = 0; m < 4; ++m)
      af[m] = *reinterpret_cast<const bf16x8*>(&Asb[(wrow + m * 16 + lr) * 32 + kslot]);
#pragma unroll
    for (int n = 0; n < 4; ++n)
      bfr[n] = *reinterpret_cast<const bf16x8*>(&Bsb[(wcol + n * 16 + lr) * 32 + kslot]);
    __builtin_amdgcn_s_setprio(1);
#pragma unroll
    for (int m = 0; m < 4; ++m)
#pragma unroll
      for (int n = 0; n < 4; ++n)
        acc[m][n] = __builtin_amdgcn_mfma_f32_16x16x32_bf16(af[m], bfr[n], acc[m][n], 0, 0, 0);
    __builtin_amdgcn_s_setprio(0);

    asm volatile("" ::: "memory");
    __builtin_amdgcn_s_barrier();
    asm volatile("" ::: "memory");
    if (c + 3 < NC) stage(c + 3, buf);
    buf = (buf == 2) ? 0 : buf + 1;
  }

  // C/D layout: col = lane&15, row = (lane>>4)*4 + reg
  const int orow = brow + wrow + ((lane >> 4) << 2);
  const int ocol = bcol + wcol + lr;
  if (MODE == 0) {
    const int wcol0 = bcol + wcol;  // 64-aligned -> exactly one head slice
    const int sect = wcol0 >> 6;    // 0..7 q, 8..15 k, 16..23 v
    const bool doln = sect < 16;
    const float* Gp = (sect < 8) ? (gq + wcol0) : (gk + (wcol0 - 512));
    const float* Pp = (sect < 8) ? (bq + wcol0) : (bk + (wcol0 - 512));
    float gv[4], pv[4];
    if (doln) {
#pragma unroll
      for (int n = 0; n < 4; ++n) { gv[n] = Gp[n * 16 + lr]; pv[n] = Pp[n * 16 + lr]; }
    }
    u16* Cp = (u16*)C;
#pragma unroll
    for (int m = 0; m < 4; ++m)
#pragma unroll
      for (int r = 0; r < 4; ++r) {
        size_t rowoff = (size_t)(orow + m * 16 + r) * N;
        if (doln) {
          float s = 0.f, s2 = 0.f;
#pragma unroll
          for (int n = 0; n < 4; ++n) {
            float x = acc[m][n][r];
            s += x; s2 += x * x;
          }
#pragma unroll
          for (int off = 8; off; off >>= 1) {
            s += __shfl_xor(s, off, 64);
            s2 += __shfl_xor(s2, off, 64);
          }
          float mean = s * 0.015625f;
          float inv = rsqrtf(s2 * 0.015625f - mean * mean + 1e-5f);
#pragma unroll
          for (int n = 0; n < 4; ++n)
            Cp[rowoff + ocol + n * 16] =
                f2b((acc[m][n][r] - mean) * inv * gv[n] + pv[n]);
        } else {
#pragma unroll
          for (int n = 0; n < 4; ++n)
            Cp[rowoff + ocol + n * 16] = f2b(acc[m][n][r]);
        }
      }
  } else {
    float bvv[4];
#pragma unroll
    for (int n = 0; n < 4; ++n) bvv[n] = bias[ocol + n * 16];
    float* Cp = (float*)C;
#pragma unroll
    for (int m = 0; m < 4; ++m)
#pragma unroll
      for (int r = 0; r < 4; ++r) {
        size_t rowoff = (size_t)(orow + m * 16 + r) * N;
#pragma unroll
        for (int n = 0; n < 4; ++n)
          Cp[rowoff + ocol + n * 16] = acc[m][n][r] + bvv[n];
      }
  }
}

// ---------- KV[b,h,d,e] += sum_n k[n,d]*v[n,e]  (atomic partials over n-chunks) ----------
__global__ __launch_bounds__(256) void kv_accum(const u16* __restrict__ qkv,
                                                float* __restrict__ KV) {
  int nch = blockIdx.x & 7;   // 8 chunks of 512 rows
  int bh = blockIdx.x >> 3;   // 0..31
  int b = bh >> 3, h = bh & 7;
  __shared__ float ks[64][64];
  __shared__ float vs[64][64];
  int tid = threadIdx.x;
  int ty = tid >> 4, tx = tid & 15;
  int rr = tid >> 2, cc = (tid & 3) * 16;
  float acc[4][4];
#pragma unroll
  for (int i = 0; i < 4; ++i)
#pragma unroll
    for (int j = 0; j < 4; ++j) acc[i][j] = 0.f;

  for (int t = 0; t < 8; ++t) {
    int n0 = nch * 512 + t * 64;
    __syncthreads();
    size_t base = ((size_t)(b * 4096 + n0 + rr)) * 1536 + h * 64 + cc;
    const uint4* kp = reinterpret_cast<const uint4*>(&qkv[base + 512]);
    const uint4* vp = reinterpret_cast<const uint4*>(&qkv[base + 1024]);
    uint4 k0 = kp[0], k1 = kp[1];
    uint4 v0 = vp[0], v1 = vp[1];
    unpack16(k0, k1, &ks[rr][cc]);
    unpack16(v0, v1, &vs[rr][cc]);
    __syncthreads();
    for (int n = 0; n < 64; ++n) {
      float4 k4 = *reinterpret_cast<const float4*>(&ks[n][ty * 4]);
      float4 v4 = *reinterpret_cast<const float4*>(&vs[n][tx * 4]);
      float ka[4] = {k4.x, k4.y, k4.z, k4.w};
      float va[4] = {v4.x, v4.y, v4.z, v4.w};
#pragma unroll
      for (int i = 0; i < 4; ++i)
#pragma unroll
        for (int j = 0; j < 4; ++j) acc[i][j] += ka[i] * va[j];
    }
  }
  float* dst = KV + (size_t)bh * 4096;
#pragma unroll
  for (int i = 0; i < 4; ++i)
#pragma unroll
    for (int j = 0; j < 4; ++j)
      atomicAdd(&dst[(ty * 4 + i) * 64 + tx * 4 + j], acc[i][j]);
}

// ---------- attn[n, h*64+e] = scale * sum_d qn[n,d] * KV[b,h,d,e] ----------
__global__ __launch_bounds__(256) void attn_kernel(const u16* __restrict__ qkv,
                                                   const float* __restrict__ KV,
                                                   u16* __restrict__ attn) {
  int rblk = blockIdx.x;  // 64 rows per block, 256 blocks
  int b = rblk >> 6;
  __shared__ float qs[64][65];
  __shared__ float kvs[64][64];
  int tid = threadIdx.x;
  int ty = tid >> 4, tx = tid & 15;
  int rr = tid >> 2, cc = (tid & 3) * 16;
  const float scale = 1.0f / 32768.0f;  // 1/(sqrt(64)*4096)
  for (int h = 0; h < 8; ++h) {
    __syncthreads();
    size_t qbase = ((size_t)(rblk * 64 + rr)) * 1536 + h * 64 + cc;
    const uint4* qp = reinterpret_cast<const uint4*>(&qkv[qbase]);
    uint4 q0 = qp[0], q1 = qp[1];
    unpack16(q0, q1, &qs[rr][cc]);
    const float4* kp =
        reinterpret_cast<const float4*>(&KV[((size_t)(b * 8 + h)) * 4096 + rr * 64 + cc]);
#pragma unroll
    for (int j = 0; j < 4; ++j) {
      float4 t = kp[j];
      kvs[rr][cc + 4 * j + 0] = t.x;
      kvs[rr][cc + 4 * j + 1] = t.y;
      kvs[rr][cc + 4 * j + 2] = t.z;
      kvs[rr][cc + 4 * j + 3] = t.w;
    }
    __syncthreads();
    float acc[4][4] = {};
    for (int d = 0; d < 64; ++d) {
      float a0 = qs[ty * 4 + 0][d], a1 = qs[ty * 4 + 1][d];
      float a2 = qs[ty * 4 + 2][d], a3 = qs[ty * 4 + 3][d];
      float4 bv = *reinterpret_cast<const float4*>(&kvs[d][tx * 4]);
      float ba[4] = {bv.x, bv.y, bv.z, bv.w};
#pragma unroll
      for (int j = 0; j < 4; ++j) {
        acc[0][j] += a0 * ba[j];
        acc[1][j] += a1 * ba[j];
        acc[2][j] += a2 * ba[j];
        acc[3][j] += a3 * ba[j];
      }
    }
#pragma unroll
    for (int i = 0; i < 4; ++i) {
      int row = rblk * 64 + ty * 4 + i;
      ushort4 o;
      o.x = f2b(acc[i][0] * scale);
      o.y = f2b(acc[i][1] * scale);
      o.z = f2b(acc[i][2] * scale);
      o.w = f2b(acc[i][3] * scale);
      *reinterpret_cast<ushort4*>(&attn[(size_t)row * 512 + h * 64 + tx * 4]) = o;
    }
  }
}

// ---------- launch ----------
extern "C" void kernel_launch(void* const* d_in, const int* in_sizes, int n_in,
                              void* d_out, int out_size, void* d_ws, size_t ws_size,
                              hipStream_t stream) {
  const float* x  = (const float*)d_in[0];
  const float* Wq = (const float*)d_in[1];
  const float* gq = (const float*)d_in[2];
  const float* bq = (const float*)d_in[3];
  const float* gk = (const float*)d_in[4];
  const float* bk = (const float*)d_in[5];
  const float* Wo = (const float*)d_in[6];
  const float* bo = (const float*)d_in[7];
  float* out = (float*)d_out;

  char* p = (char*)d_ws;
  auto carve = [&](size_t bytes) {
    char* r = p;
    p += (bytes + 255) & ~(size_t)255;
    return r;
  };
  u16* xb    = (u16*)carve((size_t)16384 * 1024 * 2);
  u16* wqb   = (u16*)carve((size_t)1536 * 1024 * 2);
  u16* wob   = (u16*)carve((size_t)1024 * 512 * 2);
  u16* qkv   = (u16*)carve((size_t)16384 * 1536 * 2);
  float* KVb = (float*)carve((size_t)32 * 64 * 64 * 4);
  u16* attn  = (u16*)carve((size_t)16384 * 512 * 2);

  hipMemsetAsync(KVb, 0, (size_t)32 * 64 * 64 * 4, stream);
  cvt_bf16<<<16384, 256, 0, stream>>>(x, xb, 4194304);
  cvt_bf16<<<1536, 256, 0, stream>>>(Wq, wqb, 393216);
  cvt_bf16<<<512, 256, 0, stream>>>(Wo, wob, 131072);
  // qkv = x @ Wqkv^T  [16384,1536], fused per-head LN on q,k
  gemm_bt<0><<<128 * 12, 256, 0, stream>>>(xb, wqb, qkv, gq, bq, gk, bk, nullptr,
                                           16384, 1536, 1024, 12);
  // KV = k^T v per (b,h)
  kv_accum<<<256, 256, 0, stream>>>(qkv, KVb);
  // attn = scale * q @ KV
  attn_kernel<<<256, 256, 0, stream>>>(qkv, KVb, attn);
  // out = attn @ Wout^T + b_out  [16384,1024] fp32
  gemm_bt<1><<<128 * 8, 256, 0, stream>>>(attn, wob, out, nullptr, nullptr, nullptr,
                                          nullptr, bo, 16384, 1024, 512, 8);
}

// Round 6
// 196.559 us; speedup vs baseline: 1.1008x; 1.0342x over previous
//
#include <hip/hip_runtime.h>
#include <stdint.h>

typedef unsigned short u16;
typedef unsigned int u32;
typedef __bf16 bf16x8 __attribute__((ext_vector_type(8)));
typedef float f32x4 __attribute__((ext_vector_type(4)));

// ---------- helpers ----------
__device__ __forceinline__ float bf2f(u16 u) {
  return __builtin_bit_cast(float, (u32)u << 16);
}
__device__ __forceinline__ u16 f2b(float f) {
  u32 u = __builtin_bit_cast(u32, f);
  u32 r = (u + 0x7fffu + ((u >> 16) & 1u)) >> 16;  // RNE
  return (u16)r;
}
__device__ __forceinline__ void gload16(const u16* g, u16* l) {
  __builtin_amdgcn_global_load_lds(
      (const __attribute__((address_space(1))) u32*)(const void*)g,
      (__attribute__((address_space(3))) u32*)(void*)l, 16, 0, 0);
}
__device__ __forceinline__ void unpack16(uint4 a, uint4 b, float* o) {
  u32 w[8] = {a.x, a.y, a.z, a.w, b.x, b.y, b.z, b.w};
#pragma unroll
  for (int i = 0; i < 8; ++i) {
    o[2 * i]     = __builtin_bit_cast(float, w[i] << 16);
    o[2 * i + 1] = __builtin_bit_cast(float, w[i] & 0xffff0000u);
  }
}

#define BAR()                                   \
  do {                                          \
    asm volatile("" ::: "memory");              \
    __builtin_amdgcn_s_barrier();               \
    asm volatile("" ::: "memory");              \
  } while (0)

// ---------- fp32 -> bf16 convert ----------
__global__ __launch_bounds__(256) void cvt_bf16(const float* __restrict__ in,
                                                u16* __restrict__ out, int n4) {
  int i = blockIdx.x * 256 + threadIdx.x;
  if (i >= n4) return;
  float4 v = reinterpret_cast<const float4*>(in)[i];
  ushort4 o;
  o.x = f2b(v.x); o.y = f2b(v.y); o.z = f2b(v.z); o.w = f2b(v.w);
  reinterpret_cast<ushort4*>(out)[i] = o;
}

// ---------- 256x256 bf16 GEMM, BK=64, 8 waves (2Mx4N), m201-style 8-phase ----------
// C[M,N] = A[M,K] * B[N,K]^T (both row-major, K contig).
// Per K-tile: 4 phases = C-quadrants (0,0),(1,0),(0,1),(1,1); 16 MFMA each.
// Staging (half-tile = 128 rows x 64 K, 16KB, 2 gload16/thread):
//   Q1: B1(t+1)  [other buf; its B1 last read at Q3 of t-1]
//   Q3: A0(t+2)  [this buf; A fully consumed after Q2's ds-reads]
//   Q4: A1(t+2), B0(t+2)  [B fully consumed after Q3's ds-reads]
// Wait: vmcnt(6) (= A0,A1,B0 of t+1 in flight) before Q4's closing barrier.
// Two barriers per phase: {reads, stage, BAR, MFMA, BAR} — the closing BAR
// makes the next phase's stage safe vs this phase's in-flight ds_reads.
// LDS swizzle: 16B-slot s -> s ^ (row&7), applied on the global SOURCE of
// global_load_lds (linear dest) and on the ds_read address.
// MODE 0: bf16 out + fused per-head LN. MODE 1: fp32 out + bias.
template <int MODE>
__global__ __launch_bounds__(512, 2) void gemm256p(
    const u16* __restrict__ A, const u16* __restrict__ B, void* __restrict__ C,
    const float* __restrict__ gq, const float* __restrict__ bq,
    const float* __restrict__ gk, const float* __restrict__ bk,
    const float* __restrict__ bias, int M, int N, int K, int ntn) {
  __shared__ u16 sm[2][2][2][128 * 64];  // [buf][A/B][half][row*64+col], 128 KiB

  // XCD-aware bijective swizzle (grid % 8 == 0 at both call sites)
  const int nwg = gridDim.x;
  const int bid0 = blockIdx.x;
  const int bid = (bid0 & 7) * (nwg >> 3) + (bid0 >> 3);
  const int tm = bid / ntn, tn = bid % ntn;
  const int TR = tm << 8, CB = tn << 8;
  const int tid = threadIdx.x;
  const int w = tid >> 6, lane = tid & 63;
  const int lr = lane & 15, lg = lane >> 4;
  const int l3 = lane >> 3;
  const int sg = (lane & 7) ^ l3;   // pre-swizzled global 16B slot for staging
  const int R0 = (w >> 2) << 7;     // wave row base (0/128)
  const int C0 = (w & 3) << 6;      // wave col base (0/64/128/192)
  const int NT = K >> 6;

  // swizzled ds_read slots (elems): slot = (kk*4+lg) ^ (row&7), row&7 == lane&7
  const int sw0 = ((lg ^ (lane & 7)) << 3);
  const int sw1 = (((4 + lg) ^ (lane & 7)) << 3);

  // stage one half-tile (128 rows x 64) of tile t into buf t&1
  auto stage_half = [&](int t, int ab, int half) {
    const int buf = t & 1;
    const u16* G = ab ? B : A;
    const int gb = ab ? CB : TR;
    const int r0 = half * 128 + w * 16;
    const u16* src = G + (size_t)(gb + r0 + l3) * K + (size_t)t * 64 + (sg << 3);
    u16* dst = &sm[buf][ab][half][(w * 16) * 64];
    gload16(src, dst);
    gload16(src + (size_t)8 * K, dst + 8 * 64);
  };

  f32x4 acc[8][4];
#pragma unroll
  for (int m = 0; m < 8; ++m)
#pragma unroll
    for (int n = 0; n < 4; ++n) acc[m][n] = (f32x4){0.f, 0.f, 0.f, 0.f};

  // prologue: tile 0 fully + A0,A1,B0 of tile 1 (7 half-tiles, 14 loads)
  stage_half(0, 0, 0);
  stage_half(0, 0, 1);
  stage_half(0, 1, 0);
  stage_half(0, 1, 1);
  if (NT > 1) {
    stage_half(1, 0, 0);
    stage_half(1, 0, 1);
    stage_half(1, 1, 0);
    asm volatile("s_waitcnt vmcnt(6)" ::: "memory");
  } else {
    asm volatile("s_waitcnt vmcnt(0)" ::: "memory");
  }
  BAR();

  bf16x8 af[2][4][2];   // both A half-quadrants held across the tile
  bf16x8 bfr[2][2];     // current-nh B frags

#define LDA(MH)                                                            \
  {                                                                        \
    const u16* Ab = &sm[buf][0][R0 >> 7][0];                               \
    _Pragma("unroll") for (int mi = 0; mi < 4; ++mi) {                     \
      int ro = (((MH) * 4 + mi) * 16 + lr) * 64;                           \
      af[MH][mi][0] = *reinterpret_cast<const bf16x8*>(&Ab[ro + sw0]);     \
      af[MH][mi][1] = *reinterpret_cast<const bf16x8*>(&Ab[ro + sw1]);     \
    }                                                                      \
  }
#define LDB(NH)                                                            \
  {                                                                        \
    const u16* Bb = &sm[buf][1][C0 >> 7][(C0 & 64) * 64];                  \
    _Pragma("unroll") for (int ni = 0; ni < 2; ++ni) {                     \
      int ro = ((NH) * 32 + ni * 16 + lr) * 64;                            \
      bfr[ni][0] = *reinterpret_cast<const bf16x8*>(&Bb[ro + sw0]);        \
      bfr[ni][1] = *reinterpret_cast<const bf16x8*>(&Bb[ro + sw1]);        \
    }                                                                      \
  }
#define MFMAQ(MH, NH)                                                      \
  {                                                                        \
    __builtin_amdgcn_s_setprio(1);                                         \
    _Pragma("unroll") for (int mi = 0; mi < 4; ++mi)                       \
      _Pragma("unroll") for (int ni = 0; ni < 2; ++ni)                     \
        _Pragma("unroll") for (int kk = 0; kk < 2; ++kk)                   \
          acc[(MH) * 4 + mi][(NH) * 2 + ni] =                              \
              __builtin_amdgcn_mfma_f32_16x16x32_bf16(                     \
                  af[MH][mi][kk], bfr[ni][kk],                             \
                  acc[(MH) * 4 + mi][(NH) * 2 + ni], 0, 0, 0);             \
    __builtin_amdgcn_s_setprio(0);                                         \
  }

  for (int t = 0; t < NT; ++t) {
    const int buf = t & 1;
    // ---- Q1: quadrant (0,0) — tile t fully resident (vmcnt+BAR at prev Q4)
    LDA(0);
    LDB(0);
    if (t + 1 < NT) stage_half(t + 1, 1, 1);  // B1(t+1)
    BAR();
    MFMAQ(0, 0);
    BAR();
    // ---- Q2: quadrant (1,0) — reuses bfr(nh0)
    LDA(1);
    BAR();
    MFMAQ(1, 0);
    BAR();
    // ---- Q3: quadrant (0,1) — A fully consumed after Q2's reads
    LDB(1);
    if (t + 2 < NT) stage_half(t + 2, 0, 0);  // A0(t+2)
    BAR();
    MFMAQ(0, 1);
    BAR();
    // ---- Q4: quadrant (1,1) — B fully consumed after Q3's reads
    if (t + 2 < NT) {
      stage_half(t + 2, 0, 1);  // A1(t+2)
      stage_half(t + 2, 1, 0);  // B0(t+2)
    }
    BAR();
    MFMAQ(1, 1);
    if (t + 1 < NT) {
      if (t + 2 < NT)
        asm volatile("s_waitcnt vmcnt(6)" ::: "memory");
      else
        asm volatile("s_waitcnt vmcnt(0)" ::: "memory");
    }
    BAR();
  }
#undef LDA
#undef LDB
#undef MFMAQ

  // ---- epilogue ----
  const int orow = TR + R0 + lg * 4;  // + m*16 + r
  const int ocol = CB + C0 + lr;      // + n*16
  if (MODE == 0) {
    const int wcol0 = CB + C0;  // 64-aligned -> exactly one head slice
    const int sect = wcol0 >> 6;
    const bool doln = sect < 16;
    const float* Gp = (sect < 8) ? (gq + wcol0) : (gk + (wcol0 - 512));
    const float* Pp = (sect < 8) ? (bq + wcol0) : (bk + (wcol0 - 512));
    float gv[4], pv[4];
    if (doln) {
#pragma unroll
      for (int n = 0; n < 4; ++n) { gv[n] = Gp[n * 16 + lr]; pv[n] = Pp[n * 16 + lr]; }
    }
    u16* Cp = (u16*)C;
#pragma unroll
    for (int m = 0; m < 8; ++m)
#pragma unroll
      for (int r = 0; r < 4; ++r) {
        size_t rowoff = (size_t)(orow + m * 16 + r) * N;
        if (doln) {
          float s = 0.f, s2 = 0.f;
#pragma unroll
          for (int n = 0; n < 4; ++n) {
            float x = acc[m][n][r];
            s += x; s2 += x * x;
          }
#pragma unroll
          for (int off = 8; off; off >>= 1) {
            s += __shfl_xor(s, off, 64);
            s2 += __shfl_xor(s2, off, 64);
          }
          float mean = s * 0.015625f;
          float inv = rsqrtf(s2 * 0.015625f - mean * mean + 1e-5f);
#pragma unroll
          for (int n = 0; n < 4; ++n)
            Cp[rowoff + ocol + n * 16] =
                f2b((acc[m][n][r] - mean) * inv * gv[n] + pv[n]);
        } else {
#pragma unroll
          for (int n = 0; n < 4; ++n)
            Cp[rowoff + ocol + n * 16] = f2b(acc[m][n][r]);
        }
      }
  } else {
    float bvv[4];
#pragma unroll
    for (int n = 0; n < 4; ++n) bvv[n] = bias[ocol + n * 16];
    float* Cp = (float*)C;
#pragma unroll
    for (int m = 0; m < 8; ++m)
#pragma unroll
      for (int r = 0; r < 4; ++r) {
        size_t rowoff = (size_t)(orow + m * 16 + r) * N;
#pragma unroll
        for (int n = 0; n < 4; ++n)
          Cp[rowoff + ocol + n * 16] = acc[m][n][r] + bvv[n];
      }
  }
}

// ---------- KV[b,h,d,e] += sum_n k[n,d]*v[n,e]  (atomic partials over n-chunks) ----------
__global__ __launch_bounds__(256) void kv_accum(const u16* __restrict__ qkv,
                                                float* __restrict__ KV) {
  int nch = blockIdx.x & 7;   // 8 chunks of 512 rows
  int bh = blockIdx.x >> 3;   // 0..31
  int b = bh >> 3, h = bh & 7;
  __shared__ float ks[64][64];
  __shared__ float vs[64][64];
  int tid = threadIdx.x;
  int ty = tid >> 4, tx = tid & 15;
  int rr = tid >> 2, cc = (tid & 3) * 16;
  float acc[4][4];
#pragma unroll
  for (int i = 0; i < 4; ++i)
#pragma unroll
    for (int j = 0; j < 4; ++j) acc[i][j] = 0.f;

  for (int t = 0; t < 8; ++t) {
    int n0 = nch * 512 + t * 64;
    __syncthreads();
    size_t base = ((size_t)(b * 4096 + n0 + rr)) * 1536 + h * 64 + cc;
    const uint4* kp = reinterpret_cast<const uint4*>(&qkv[base + 512]);
    const uint4* vp = reinterpret_cast<const uint4*>(&qkv[base + 1024]);
    uint4 k0 = kp[0], k1 = kp[1];
    uint4 v0 = vp[0], v1 = vp[1];
    unpack16(k0, k1, &ks[rr][cc]);
    unpack16(v0, v1, &vs[rr][cc]);
    __syncthreads();
    for (int n = 0; n < 64; ++n) {
      float4 k4 = *reinterpret_cast<const float4*>(&ks[n][ty * 4]);
      float4 v4 = *reinterpret_cast<const float4*>(&vs[n][tx * 4]);
      float ka[4] = {k4.x, k4.y, k4.z, k4.w};
      float va[4] = {v4.x, v4.y, v4.z, v4.w};
#pragma unroll
      for (int i = 0; i < 4; ++i)
#pragma unroll
        for (int j = 0; j < 4; ++j) acc[i][j] += ka[i] * va[j];
    }
  }
  float* dst = KV + (size_t)bh * 4096;
#pragma unroll
  for (int i = 0; i < 4; ++i)
#pragma unroll
    for (int j = 0; j < 4; ++j)
      atomicAdd(&dst[(ty * 4 + i) * 64 + tx * 4 + j], acc[i][j]);
}

// ---------- attn[n, h*64+e] = scale * sum_d qn[n,d] * KV[b,h,d,e] ----------
__global__ __launch_bounds__(256) void attn_kernel(const u16* __restrict__ qkv,
                                                   const float* __restrict__ KV,
                                                   u16* __restrict__ attn) {
  int rblk = blockIdx.x;  // 64 rows per block, 256 blocks
  int b = rblk >> 6;
  __shared__ float qs[64][65];
  __shared__ float kvs[64][64];
  int tid = threadIdx.x;
  int ty = tid >> 4, tx = tid & 15;
  int rr = tid >> 2, cc = (tid & 3) * 16;
  const float scale = 1.0f / 32768.0f;  // 1/(sqrt(64)*4096)
  for (int h = 0; h < 8; ++h) {
    __syncthreads();
    size_t qbase = ((size_t)(rblk * 64 + rr)) * 1536 + h * 64 + cc;
    const uint4* qp = reinterpret_cast<const uint4*>(&qkv[qbase]);
    uint4 q0 = qp[0], q1 = qp[1];
    unpack16(q0, q1, &qs[rr][cc]);
    const float4* kp =
        reinterpret_cast<const float4*>(&KV[((size_t)(b * 8 + h)) * 4096 + rr * 64 + cc]);
#pragma unroll
    for (int j = 0; j < 4; ++j) {
      float4 t = kp[j];
      kvs[rr][cc + 4 * j + 0] = t.x;
      kvs[rr][cc + 4 * j + 1] = t.y;
      kvs[rr][cc + 4 * j + 2] = t.z;
      kvs[rr][cc + 4 * j + 3] = t.w;
    }
    __syncthreads();
    float acc[4][4] = {};
    for (int d = 0; d < 64; ++d) {
      float a0 = qs[ty * 4 + 0][d], a1 = qs[ty * 4 + 1][d];
      float a2 = qs[ty * 4 + 2][d], a3 = qs[ty * 4 + 3][d];
      float4 bv = *reinterpret_cast<const float4*>(&kvs[d][tx * 4]);
      float ba[4] = {bv.x, bv.y, bv.z, bv.w};
#pragma unroll
      for (int j = 0; j < 4; ++j) {
        acc[0][j] += a0 * ba[j];
        acc[1][j] += a1 * ba[j];
        acc[2][j] += a2 * ba[j];
        acc[3][j] += a3 * ba[j];
      }
    }
#pragma unroll
    for (int i = 0; i < 4; ++i) {
      int row = rblk * 64 + ty * 4 + i;
      ushort4 o;
      o.x = f2b(acc[i][0] * scale);
      o.y = f2b(acc[i][1] * scale);
      o.z = f2b(acc[i][2] * scale);
      o.w = f2b(acc[i][3] * scale);
      *reinterpret_cast<ushort4*>(&attn[(size_t)row * 512 + h * 64 + tx * 4]) = o;
    }
  }
}

// ---------- launch ----------
extern "C" void kernel_launch(void* const* d_in, const int* in_sizes, int n_in,
                              void* d_out, int out_size, void* d_ws, size_t ws_size,
                              hipStream_t stream) {
  const float* x  = (const float*)d_in[0];
  const float* Wq = (const float*)d_in[1];
  const float* gq = (const float*)d_in[2];
  const float* bq = (const float*)d_in[3];
  const float* gk = (const float*)d_in[4];
  const float* bk = (const float*)d_in[5];
  const float* Wo = (const float*)d_in[6];
  const float* bo = (const float*)d_in[7];
  float* out = (float*)d_out;

  char* p = (char*)d_ws;
  auto carve = [&](size_t bytes) {
    char* r = p;
    p += (bytes + 255) & ~(size_t)255;
    return r;
  };
  u16* xb    = (u16*)carve((size_t)16384 * 1024 * 2);
  u16* wqb   = (u16*)carve((size_t)1536 * 1024 * 2);
  u16* wob   = (u16*)carve((size_t)1024 * 512 * 2);
  u16* qkv   = (u16*)carve((size_t)16384 * 1536 * 2);
  float* KVb = (float*)carve((size_t)32 * 64 * 64 * 4);
  u16* attn  = (u16*)carve((size_t)16384 * 512 * 2);

  hipMemsetAsync(KVb, 0, (size_t)32 * 64 * 64 * 4, stream);
  cvt_bf16<<<16384, 256, 0, stream>>>(x, xb, 4194304);
  cvt_bf16<<<1536, 256, 0, stream>>>(Wq, wqb, 393216);
  cvt_bf16<<<512, 256, 0, stream>>>(Wo, wob, 131072);
  // qkv = x @ Wqkv^T  [16384,1536], fused per-head LN on q,k
  gemm256p<0><<<64 * 6, 512, 0, stream>>>(xb, wqb, qkv, gq, bq, gk, bk, nullptr,
                                          16384, 1536, 1024, 6);
  // KV = k^T v per (b,h)
  kv_accum<<<256, 256, 0, stream>>>(qkv, KVb);
  // attn = scale * q @ KV
  attn_kernel<<<256, 256, 0, stream>>>(qkv, KVb, attn);
  // out = attn @ Wout^T + b_out  [16384,1024] fp32
  gemm256p<1><<<64 * 4, 512, 0, stream>>>(attn, wob, out, nullptr, nullptr, nullptr,
                                          nullptr, bo, 16384, 1024, 512, 4);
}

// Round 7
// 190.958 us; speedup vs baseline: 1.1331x; 1.0293x over previous
//
#include <hip/hip_runtime.h>
#include <stdint.h>

typedef unsigned short u16;
typedef unsigned int u32;
typedef __bf16 bf16x8 __attribute__((ext_vector_type(8)));
typedef float f32x4 __attribute__((ext_vector_type(4)));

// ---------- helpers ----------
__device__ __forceinline__ float bf2f(u16 u) {
  return __builtin_bit_cast(float, (u32)u << 16);
}
__device__ __forceinline__ u16 f2b(float f) {
  u32 u = __builtin_bit_cast(u32, f);
  u32 r = (u + 0x7fffu + ((u >> 16) & 1u)) >> 16;  // RNE
  return (u16)r;
}
__device__ __forceinline__ void gload16(const u16* g, u16* l) {
  __builtin_amdgcn_global_load_lds(
      (const __attribute__((address_space(1))) u32*)(const void*)g,
      (__attribute__((address_space(3))) u32*)(void*)l, 16, 0, 0);
}
__device__ __forceinline__ void unpack16(uint4 a, uint4 b, float* o) {
  u32 w[8] = {a.x, a.y, a.z, a.w, b.x, b.y, b.z, b.w};
#pragma unroll
  for (int i = 0; i < 8; ++i) {
    o[2 * i]     = __builtin_bit_cast(float, w[i] << 16);
    o[2 * i + 1] = __builtin_bit_cast(float, w[i] & 0xffff0000u);
  }
}

// ---------- fp32 -> bf16 convert ----------
__global__ __launch_bounds__(256) void cvt_bf16(const float* __restrict__ in,
                                                u16* __restrict__ out, int n4) {
  int i = blockIdx.x * 256 + threadIdx.x;
  if (i >= n4) return;
  float4 v = reinterpret_cast<const float4*>(in)[i];
  ushort4 o;
  o.x = f2b(v.x); o.y = f2b(v.y); o.z = f2b(v.z); o.w = f2b(v.w);
  reinterpret_cast<ushort4*>(out)[i] = o;
}

// ---------- bf16 GEMM  C[M,N] = A[M,K] * B[N,K]^T ----------
// 128x128 tile, BK=32, 4 waves (2x2), 16x16x32 MFMA, double-buffered LDS.
// One __syncthreads per K-tile: {stage(t+1)->buf[nxt]; ds_read frags(t);
// 16 MFMA; sync}. The sync's implicit vmcnt(0) drains loads issued a full
// tile earlier (covered by reads+MFMA). Stage overwrite of buf[t-1] is safe:
// its reads completed before the end-of-(t-1) sync.
// LDS swizzle: 16B-slot s -> s ^ (row&3); pre-swizzled global source
// (linear global_load_lds dest) + same XOR on ds_read.
// MODE 0: bf16 out + fused per-head LN. MODE 1: fp32 out + bias.
template <int MODE>
__global__ __launch_bounds__(256, 3) void gemm_bt(
    const u16* __restrict__ A, const u16* __restrict__ B, void* __restrict__ C,
    const float* __restrict__ gq, const float* __restrict__ bq,
    const float* __restrict__ gk, const float* __restrict__ bk,
    const float* __restrict__ bias, int M, int N, int K, int ntn) {
  __shared__ u16 As[2][128 * 32];
  __shared__ u16 Bs[2][128 * 32];

  // XCD-aware bijective swizzle (grid % 8 == 0 at both call sites)
  const int nwg = gridDim.x;
  const int bid0 = blockIdx.x;
  const int bid = (bid0 & 7) * (nwg >> 3) + (bid0 >> 3);
  const int tm = bid / ntn, tn = bid % ntn;
  const int brow = tm << 7, bcol = tn << 7;
  const int tid = threadIdx.x;
  const int w = tid >> 6, lane = tid & 63;
  const int wrow = (w >> 1) << 6, wcol = (w & 1) << 6;
  const int lr = lane & 15, lg = lane >> 4;

  // staging: lane covers (row = 16g + lane/4, slot = lane&3); global source
  // slot pre-swizzled: (lane&3) ^ (row&3), row&3 = (lane>>2)&3.
  const int sslot = (lane & 3) ^ ((lane >> 2) & 3);
  const u16* Asrc = A + (size_t)(brow + (lane >> 2)) * K + sslot * 8;
  const u16* Bsrc = B + (size_t)(bcol + (lane >> 2)) * K + sslot * 8;

  auto stage = [&](int t, int buf) {
    const int k0 = t << 5;
#pragma unroll
    for (int i = 0; i < 2; ++i) {
      int g = w + 4 * i;  // wave-uniform row-group (16 rows, 1 KiB)
      gload16(Asrc + (size_t)(16 * g) * K + k0, &As[buf][(16 * g) * 32]);
      gload16(Bsrc + (size_t)(16 * g) * K + k0, &Bs[buf][(16 * g) * 32]);
    }
  };

  f32x4 acc[4][4];
#pragma unroll
  for (int m = 0; m < 4; ++m)
#pragma unroll
    for (int n = 0; n < 4; ++n) acc[m][n] = (f32x4){0.f, 0.f, 0.f, 0.f};

  const int NC = K >> 5;
  // swizzled ds_read 16B-slot (elems): lg ^ (row&3), row&3 == lr&3
  const int kslot = (lg ^ (lr & 3)) << 3;

  stage(0, 0);
  __syncthreads();

  for (int t = 0; t < NC; ++t) {
    const int cur = t & 1;
    if (t + 1 < NC) stage(t + 1, cur ^ 1);

    const u16* Asb = As[cur];
    const u16* Bsb = Bs[cur];
    bf16x8 af[4], bfr[4];
#pragma unroll
    for (int m = 0; m < 4; ++m)
      af[m] = *reinterpret_cast<const bf16x8*>(&Asb[(wrow + m * 16 + lr) * 32 + kslot]);
#pragma unroll
    for (int n = 0; n < 4; ++n)
      bfr[n] = *reinterpret_cast<const bf16x8*>(&Bsb[(wcol + n * 16 + lr) * 32 + kslot]);
    __builtin_amdgcn_s_setprio(1);
#pragma unroll
    for (int m = 0; m < 4; ++m)
#pragma unroll
      for (int n = 0; n < 4; ++n)
        acc[m][n] = __builtin_amdgcn_mfma_f32_16x16x32_bf16(af[m], bfr[n], acc[m][n], 0, 0, 0);
    __builtin_amdgcn_s_setprio(0);
    __syncthreads();  // implicit vmcnt(0): drains stage(t+1), full-tile cover
  }

  // C/D layout: col = lane&15, row = (lane>>4)*4 + reg
  const int orow = brow + wrow + ((lane >> 4) << 2);
  const int ocol = bcol + wcol + lr;
  if (MODE == 0) {
    const int wcol0 = bcol + wcol;  // 64-aligned -> exactly one head slice
    const int sect = wcol0 >> 6;    // 0..7 q, 8..15 k, 16..23 v
    const bool doln = sect < 16;
    const float* Gp = (sect < 8) ? (gq + wcol0) : (gk + (wcol0 - 512));
    const float* Pp = (sect < 8) ? (bq + wcol0) : (bk + (wcol0 - 512));
    float gv[4], pv[4];
    if (doln) {
#pragma unroll
      for (int n = 0; n < 4; ++n) { gv[n] = Gp[n * 16 + lr]; pv[n] = Pp[n * 16 + lr]; }
    }
    u16* Cp = (u16*)C;
#pragma unroll
    for (int m = 0; m < 4; ++m)
#pragma unroll
      for (int r = 0; r < 4; ++r) {
        size_t rowoff = (size_t)(orow + m * 16 + r) * N;
        if (doln) {
          float s = 0.f, s2 = 0.f;
#pragma unroll
          for (int n = 0; n < 4; ++n) {
            float x = acc[m][n][r];
            s += x; s2 += x * x;
          }
#pragma unroll
          for (int off = 8; off; off >>= 1) {
            s += __shfl_xor(s, off, 64);
            s2 += __shfl_xor(s2, off, 64);
          }
          float mean = s * 0.015625f;
          float inv = rsqrtf(s2 * 0.015625f - mean * mean + 1e-5f);
#pragma unroll
          for (int n = 0; n < 4; ++n)
            Cp[rowoff + ocol + n * 16] =
                f2b((acc[m][n][r] - mean) * inv * gv[n] + pv[n]);
        } else {
#pragma unroll
          for (int n = 0; n < 4; ++n)
            Cp[rowoff + ocol + n * 16] = f2b(acc[m][n][r]);
        }
      }
  } else {
    float bvv[4];
#pragma unroll
    for (int n = 0; n < 4; ++n) bvv[n] = bias[ocol + n * 16];
    float* Cp = (float*)C;
#pragma unroll
    for (int m = 0; m < 4; ++m)
#pragma unroll
      for (int r = 0; r < 4; ++r) {
        size_t rowoff = (size_t)(orow + m * 16 + r) * N;
#pragma unroll
        for (int n = 0; n < 4; ++n)
          Cp[rowoff + ocol + n * 16] = acc[m][n][r] + bvv[n];
      }
  }
}

// ---------- KV[b,h,d,e] += sum_n k[n,d]*v[n,e]  (atomic partials over n-chunks) ----------
__global__ __launch_bounds__(256) void kv_accum(const u16* __restrict__ qkv,
                                                float* __restrict__ KV) {
  int nch = blockIdx.x & 7;   // 8 chunks of 512 rows
  int bh = blockIdx.x >> 3;   // 0..31
  int b = bh >> 3, h = bh & 7;
  __shared__ float ks[64][64];
  __shared__ float vs[64][64];
  int tid = threadIdx.x;
  int ty = tid >> 4, tx = tid & 15;
  int rr = tid >> 2, cc = (tid & 3) * 16;
  float acc[4][4];
#pragma unroll
  for (int i = 0; i < 4; ++i)
#pragma unroll
    for (int j = 0; j < 4; ++j) acc[i][j] = 0.f;

  for (int t = 0; t < 8; ++t) {
    int n0 = nch * 512 + t * 64;
    __syncthreads();
    size_t base = ((size_t)(b * 4096 + n0 + rr)) * 1536 + h * 64 + cc;
    const uint4* kp = reinterpret_cast<const uint4*>(&qkv[base + 512]);
    const uint4* vp = reinterpret_cast<const uint4*>(&qkv[base + 1024]);
    uint4 k0 = kp[0], k1 = kp[1];
    uint4 v0 = vp[0], v1 = vp[1];
    unpack16(k0, k1, &ks[rr][cc]);
    unpack16(v0, v1, &vs[rr][cc]);
    __syncthreads();
    for (int n = 0; n < 64; ++n) {
      float4 k4 = *reinterpret_cast<const float4*>(&ks[n][ty * 4]);
      float4 v4 = *reinterpret_cast<const float4*>(&vs[n][tx * 4]);
      float ka[4] = {k4.x, k4.y, k4.z, k4.w};
      float va[4] = {v4.x, v4.y, v4.z, v4.w};
#pragma unroll
      for (int i = 0; i < 4; ++i)
#pragma unroll
        for (int j = 0; j < 4; ++j) acc[i][j] += ka[i] * va[j];
    }
  }
  float* dst = KV + (size_t)bh * 4096;
#pragma unroll
  for (int i = 0; i < 4; ++i)
#pragma unroll
    for (int j = 0; j < 4; ++j)
      atomicAdd(&dst[(ty * 4 + i) * 64 + tx * 4 + j], acc[i][j]);
}

// ---------- attn[n, h*64+e] = scale * sum_d qn[n,d] * KV[b,h,d,e] ----------
__global__ __launch_bounds__(256) void attn_kernel(const u16* __restrict__ qkv,
                                                   const float* __restrict__ KV,
                                                   u16* __restrict__ attn) {
  int rblk = blockIdx.x;  // 64 rows per block, 256 blocks
  int b = rblk >> 6;
  __shared__ float qs[64][65];
  __shared__ float kvs[64][64];
  int tid = threadIdx.x;
  int ty = tid >> 4, tx = tid & 15;
  int rr = tid >> 2, cc = (tid & 3) * 16;
  const float scale = 1.0f / 32768.0f;  // 1/(sqrt(64)*4096)
  for (int h = 0; h < 8; ++h) {
    __syncthreads();
    size_t qbase = ((size_t)(rblk * 64 + rr)) * 1536 + h * 64 + cc;
    const uint4* qp = reinterpret_cast<const uint4*>(&qkv[qbase]);
    uint4 q0 = qp[0], q1 = qp[1];
    unpack16(q0, q1, &qs[rr][cc]);
    const float4* kp =
        reinterpret_cast<const float4*>(&KV[((size_t)(b * 8 + h)) * 4096 + rr * 64 + cc]);
#pragma unroll
    for (int j = 0; j < 4; ++j) {
      float4 t = kp[j];
      kvs[rr][cc + 4 * j + 0] = t.x;
      kvs[rr][cc + 4 * j + 1] = t.y;
      kvs[rr][cc + 4 * j + 2] = t.z;
      kvs[rr][cc + 4 * j + 3] = t.w;
    }
    __syncthreads();
    float acc[4][4] = {};
    for (int d = 0; d < 64; ++d) {
      float a0 = qs[ty * 4 + 0][d], a1 = qs[ty * 4 + 1][d];
      float a2 = qs[ty * 4 + 2][d], a3 = qs[ty * 4 + 3][d];
      float4 bv = *reinterpret_cast<const float4*>(&kvs[d][tx * 4]);
      float ba[4] = {bv.x, bv.y, bv.z, bv.w};
#pragma unroll
      for (int j = 0; j < 4; ++j) {
        acc[0][j] += a0 * ba[j];
        acc[1][j] += a1 * ba[j];
        acc[2][j] += a2 * ba[j];
        acc[3][j] += a3 * ba[j];
      }
    }
#pragma unroll
    for (int i = 0; i < 4; ++i) {
      int row = rblk * 64 + ty * 4 + i;
      ushort4 o;
      o.x = f2b(acc[i][0] * scale);
      o.y = f2b(acc[i][1] * scale);
      o.z = f2b(acc[i][2] * scale);
      o.w = f2b(acc[i][3] * scale);
      *reinterpret_cast<ushort4*>(&attn[(size_t)row * 512 + h * 64 + tx * 4]) = o;
    }
  }
}

// ---------- launch ----------
extern "C" void kernel_launch(void* const* d_in, const int* in_sizes, int n_in,
                              void* d_out, int out_size, void* d_ws, size_t ws_size,
                              hipStream_t stream) {
  const float* x  = (const float*)d_in[0];
  const float* Wq = (const float*)d_in[1];
  const float* gq = (const float*)d_in[2];
  const float* bq = (const float*)d_in[3];
  const float* gk = (const float*)d_in[4];
  const float* bk = (const float*)d_in[5];
  const float* Wo = (const float*)d_in[6];
  const float* bo = (const float*)d_in[7];
  float* out = (float*)d_out;

  char* p = (char*)d_ws;
  auto carve = [&](size_t bytes) {
    char* r = p;
    p += (bytes + 255) & ~(size_t)255;
    return r;
  };
  u16* xb    = (u16*)carve((size_t)16384 * 1024 * 2);
  u16* wqb   = (u16*)carve((size_t)1536 * 1024 * 2);
  u16* wob   = (u16*)carve((size_t)1024 * 512 * 2);
  u16* qkv   = (u16*)carve((size_t)16384 * 1536 * 2);
  float* KVb = (float*)carve((size_t)32 * 64 * 64 * 4);
  u16* attn  = (u16*)carve((size_t)16384 * 512 * 2);

  hipMemsetAsync(KVb, 0, (size_t)32 * 64 * 64 * 4, stream);
  cvt_bf16<<<16384, 256, 0, stream>>>(x, xb, 4194304);
  cvt_bf16<<<1536, 256, 0, stream>>>(Wq, wqb, 393216);
  cvt_bf16<<<512, 256, 0, stream>>>(Wo, wob, 131072);
  // qkv = x @ Wqkv^T  [16384,1536], fused per-head LN on q,k
  gemm_bt<0><<<128 * 12, 256, 0, stream>>>(xb, wqb, qkv, gq, bq, gk, bk, nullptr,
                                           16384, 1536, 1024, 12);
  // KV = k^T v per (b,h)
  kv_accum<<<256, 256, 0, stream>>>(qkv, KVb);
  // attn = scale * q @ KV
  attn_kernel<<<256, 256, 0, stream>>>(qkv, KVb, attn);
  // out = attn @ Wout^T + b_out  [16384,1024] fp32
  gemm_bt<1><<<128 * 8, 256, 0, stream>>>(attn, wob, out, nullptr, nullptr, nullptr,
                                          nullptr, bo, 16384, 1024, 512, 8);
}